// Round 5
// baseline (1159.803 us; speedup 1.0000x reference)
//
#include <hip/hip_runtime.h>
#include <stdint.h>

// ---------------- problem constants ----------------
#define NN   10000
#define NE   320000
#define K1   704    // V1 width: 256(G1)+256(G2)+32(T1)+88(T2)+64(x)+1(bias)+7 pad
#define K2V  1408   // V2 width: 1024(G3)+256(G4)+32(T3)+88(T4)+1(bias)+7 pad

#define FNEG (-1.0e30f)

typedef unsigned short u16;
typedef unsigned int   u32;

__device__ __forceinline__ float b2f(u16 v){ u32 u = ((u32)v) << 16; return __uint_as_float(u); }
__device__ __forceinline__ u16 f2b(float f){
  u32 u = __float_as_uint(f);
  u32 r = (u + 0x7fffu + ((u >> 16) & 1u)) >> 16;
  return (u16)r;
}
// dtype-adaptive scalar float load: bf=1 -> bf16 u16, bf=0 -> f32
__device__ __forceinline__ float ldf(const void* p, size_t i, int bf){
  if (bf){ u32 u = ((u32)((const u16*)p)[i]) << 16; return __uint_as_float(u); }
  return ((const float*)p)[i];
}
// width-adaptive int load: w64=1 -> int64 storage (read low word)
__device__ __forceinline__ int geti(const int* p, size_t i, int w64){
  return w64 ? p[2 * i] : p[i];
}

// folded-weight f32 region offsets (floats)
#define FW_W1A  0
#define FW_W1D  256
#define FW_WA12 512
#define FW_ETA1 1024
#define FW_ETA2 1112
#define FW_NTS1 1200
#define FW_NTD1 1232
#define FW_W2A  1264
#define FW_W2D  2288
#define FW_NTS2 3312
#define FW_NTD2 3344

// workspace byte offsets; total = 36,417,376 bytes (~36.4 MB)
#define WS_FLG   0u
#define WS_DEG   16u
#define WS_OFF   40016u
#define WS_CUR   80032u
#define WS_META  120032u
#define WS_EL    5240032u
#define WS_S1    15480032u
#define WS_D1    15640032u
#define WS_S2    15800032u
#define WS_D2    15960032u
#define WS_FW    16120032u
#define WS_M1T   16136032u
#define WS_M2T   16496480u
#define WS_HBUF  17217376u
#define WS_V     22337376u   // 14,080,000 B: V1 (10000x704) or V2 chunk (5000x1408)

// ---------------- runtime dtype/width probe ----------------
__global__ void k_probe(const u16* x16, const int* ei, const int* nt, const int* et, int4* flg){
  if (threadIdx.x == 0 && blockIdx.x == 0){
    int okb = 1;
    for (int i = 0; i < 64; i++){
      u16 u = x16[i]; int e = (u >> 7) & 0xFF;
      if (!(e >= 90 && e <= 160)){ okb = 0; break; }
    }
    int ei64 = 1, nt64 = 1, et64 = 1;
    for (int i = 0; i < 32; i++){
      if (ei[2 * i + 1] != 0) ei64 = 0;
      if (nt[2 * i + 1] != 0) nt64 = 0;
      if (et[2 * i + 1] != 0) et64 = 0;
    }
    int4 f; f.x = okb; f.y = ei64; f.z = nt64; f.w = et64;
    *flg = f;
  }
}

// ---------------- CSR build ----------------
__global__ void k_zero(int* deg){
  int t = blockIdx.x * 256 + threadIdx.x;
  if (t < NN) deg[t] = 0;
}

__global__ void k_hist(const int* ei, int* deg, const int4* flg){
  int4 f = *flg;
  int e = blockIdx.x * 256 + threadIdx.x;
  if (e < NE){ int dst = geti(ei, NE + e, f.y); atomicAdd(&deg[dst], 1); }
}

__global__ void k_scan(const int* deg, int* off, int* cursor){
  __shared__ int part[256];
  int t = threadIdx.x;
  int base = t * 40;
  int s = 0;
  for (int i = 0; i < 40; i++){ int idx = base + i; s += (idx < NN) ? deg[idx] : 0; }
  part[t] = s;
  __syncthreads();
  for (int d = 1; d < 256; d <<= 1){
    int v = (t >= d) ? part[t - d] : 0;
    __syncthreads();
    part[t] += v;
    __syncthreads();
  }
  int run = (t == 0) ? 0 : part[t - 1];
  for (int i = 0; i < 40; i++){
    int idx = base + i;
    if (idx < NN){ off[idx] = run; cursor[idx] = run; run += deg[idx]; }
  }
  if (t == 255) off[NN] = part[255];
}

__global__ void k_scatter(const int* ei, const int* ntype, const int* etype,
                          int* cursor, int4* meta, const int4* flg){
  int4 f = *flg;
  int e = blockIdx.x * 256 + threadIdx.x;
  if (e < NE){
    int src = geti(ei, e, f.y), dst = geti(ei, NE + e, f.y);
    int pos = atomicAdd(&cursor[dst], 1);
    int4 m; m.x = e; m.y = src; m.z = geti(etype, e, f.w); m.w = geti(ntype, src, f.z);
    meta[pos] = m;
  }
}

// ---------------- weight folding ----------------
__global__ void k_fold_a(const void* W1, const void* Wedge1, const void* asrc1, const void* adst1,
                         const void* aedge1, const void* etemb1,
                         const void* W2, const void* Wedge2, const void* asrc2, const void* adst2,
                         const void* aedge2, const void* etemb2, float* fw, const int4* flg){
  int bf = flg->x;
  int s = blockIdx.x * 256 + threadIdx.x;
  if (s < 256){            // W1a / W1d
    int k = s >> 2, h = s & 3; float a = 0.f, d = 0.f;
    for (int c = 0; c < 64; c++){
      float w = ldf(W1, k * 256 + h * 64 + c, bf);
      a += w * ldf(asrc1, h * 64 + c, bf); d += w * ldf(adst1, h * 64 + c, bf);
    }
    fw[FW_W1A + k * 4 + h] = a; fw[FW_W1D + k * 4 + h] = d;
  } else if (s < 768){     // wa12 [64][8]
    int q = s - 256; int k = q >> 3, dd = q & 7; float a = 0.f;
    if (dd < 4){
      for (int c = 0; c < 64; c++) a += ldf(Wedge1, k * 256 + dd * 64 + c, bf) * ldf(aedge1, dd * 64 + c, bf);
    } else {
      int h = dd - 4;
      for (int c = 0; c < 256; c++) a += ldf(Wedge2, k * 1024 + h * 256 + c, bf) * ldf(aedge2, h * 256 + c, bf);
    }
    fw[FW_WA12 + k * 8 + dd] = a;
  } else if (s < 856){     // eta1 [22][4]
    int q = s - 768; int te = q >> 2, h = q & 3; float a = 0.f;
    for (int c = 0; c < 64; c++) a += ldf(etemb1, te * 256 + h * 64 + c, bf) * ldf(aedge1, h * 64 + c, bf);
    fw[FW_ETA1 + te * 4 + h] = a;
  } else if (s < 944){     // eta2 [22][4]
    int q = s - 856; int te = q >> 2, h = q & 3; float a = 0.f;
    for (int c = 0; c < 256; c++) a += ldf(etemb2, te * 1024 + h * 256 + c, bf) * ldf(aedge2, h * 256 + c, bf);
    fw[FW_ETA2 + te * 4 + h] = a;
  } else if (s < 1968){    // W2a / W2d [256][4]
    int q = s - 944; int k = q >> 2, h = q & 3; float a = 0.f, d = 0.f;
    for (int c = 0; c < 256; c++){
      float w = ldf(W2, k * 1024 + h * 256 + c, bf);
      a += w * ldf(asrc2, h * 256 + c, bf); d += w * ldf(adst2, h * 256 + c, bf);
    }
    fw[FW_W2A + k * 4 + h] = a; fw[FW_W2D + k * 4 + h] = d;
  }
}

__global__ void k_fold_b(const void* ntemb1, const void* ntemb2, float* fw, const int4* flg){
  int bf = flg->x;
  int t = threadIdx.x;   // 64 threads
  if (t < 32){
    int te = t >> 2, h = t & 3; float a = 0.f, d = 0.f;
    for (int k = 0; k < 64; k++){
      float x = ldf(ntemb1, te * 64 + k, bf);
      a += x * fw[FW_W1A + k * 4 + h]; d += x * fw[FW_W1D + k * 4 + h];
    }
    fw[FW_NTS1 + te * 4 + h] = a; fw[FW_NTD1 + te * 4 + h] = d;
  } else {
    int q = t - 32; int te = q >> 2, h = q & 3; float a = 0.f, d = 0.f;
    for (int k = 0; k < 256; k++){
      float x = ldf(ntemb2, te * 256 + k, bf);
      a += x * fw[FW_W2A + k * 4 + h]; d += x * fw[FW_W2D + k * 4 + h];
    }
    fw[FW_NTS2 + te * 4 + h] = a; fw[FW_NTD2 + te * 4 + h] = d;
  }
}

// ---------------- combined-weight matrices (stored transposed: [col][row]) ----------------
__global__ void k_m1t(const void* W1, const void* Wedge1, const void* ntemb1, const void* etemb1,
                      const void* res1, const void* b1, u16* M1T, const int4* flg){
  int bf = flg->x;
  int c = blockIdx.x; int t = threadIdx.x; int ch = c >> 6;
  for (int r = t; r < K1; r += 256){
    float v = 0.f;
    if (r < 256){ int h = r >> 6, k = r & 63; v = (h == ch) ? ldf(W1, k * 256 + c, bf) : 0.f; }
    else if (r < 512){ int q = r - 256; int h = q >> 6, k = q & 63; v = (h == ch) ? ldf(Wedge1, k * 256 + c, bf) : 0.f; }
    else if (r < 544){ int q = r - 512; int h = q >> 3, te = q & 7;
      if (h == ch){ float a = 0.f; for (int k = 0; k < 64; k++) a += ldf(ntemb1, te * 64 + k, bf) * ldf(W1, k * 256 + c, bf); v = a; } }
    else if (r < 632){ int q = r - 544; int h = q / 22, te = q % 22; v = (h == ch) ? ldf(etemb1, te * 256 + c, bf) : 0.f; }
    else if (r < 696){ int k = r - 632; v = ldf(res1, k * 256 + c, bf); }
    else if (r == 696){ v = ldf(b1, c, bf); }
    M1T[c * K1 + r] = f2b(v);
  }
}

__global__ void k_m2t(const void* W2, const void* Wedge2, const void* ntemb2, const void* etemb2,
                      const void* b2, u16* M2T, const int4* flg){
  int bf = flg->x;
  int c = blockIdx.x; int t = threadIdx.x;
  for (int r = t; r < K2V; r += 256){
    float v = 0.f;
    if (r < 1024){ int h = r >> 8, k = r & 255; v = 0.25f * ldf(W2, k * 1024 + h * 256 + c, bf); }
    else if (r < 1280){ int q = r - 1024; int h = q >> 6, k = q & 63; v = 0.25f * ldf(Wedge2, k * 1024 + h * 256 + c, bf); }
    else if (r < 1312){ int q = r - 1280; int h = q >> 3, te = q & 7; float a = 0.f;
      for (int k = 0; k < 256; k++) a += ldf(ntemb2, te * 256 + k, bf) * ldf(W2, k * 1024 + h * 256 + c, bf);
      v = 0.25f * a; }
    else if (r < 1400){ int q = r - 1312; int h = q / 22, te = q % 22; v = 0.25f * ldf(etemb2, te * 1024 + h * 256 + c, bf); }
    else if (r == 1400){ v = ldf(b2, c, bf); }
    M2T[c * K2V + r] = f2b(v);
  }
}

// ---------------- per-node attention scalars ----------------
__global__ void k_sd1(const void* x, const int* ntype, const float* fw, float* s1, float* d1,
                      const int4* flg){
  int4 f = *flg;
  int id = blockIdx.x * 256 + threadIdx.x;
  if (id >= NN * 4) return;
  int n = id >> 2, h = id & 3;
  float a = 0.f, d = 0.f;
  for (int k = 0; k < 64; k++){
    float xv = ldf(x, (size_t)n * 64 + k, f.x);
    a += xv * fw[FW_W1A + k * 4 + h]; d += xv * fw[FW_W1D + k * 4 + h];
  }
  int nt = geti(ntype, n, f.z);
  s1[id] = a + fw[FW_NTS1 + nt * 4 + h];
  d1[id] = d + fw[FW_NTD1 + nt * 4 + h];
}

__global__ void k_sd2(const u16* hbuf, const int* ntype, const float* fw, float* s2, float* d2,
                      const int4* flg){
  int4 f = *flg;
  int id = blockIdx.x * 256 + threadIdx.x;
  if (id >= NN * 4) return;
  int n = id >> 2, h = id & 3;
  float a = 0.f, d = 0.f;
  for (int k = 0; k < 256; k++){
    float xv = b2f(hbuf[n * 256 + k]);
    a += xv * fw[FW_W2A + k * 4 + h]; d += xv * fw[FW_W2D + k * 4 + h];
  }
  int nt = geti(ntype, n, f.z);
  s2[id] = a + fw[FW_NTS2 + nt * 4 + h];
  d2[id] = d + fw[FW_NTD2 + nt * 4 + h];
}

// ---------------- edge attention-logit contributions (both layers) ----------------
__global__ void k_el(const void* ea, const int* etype, const float* fw, float* el, const int4* flg){
  __shared__ float sw[512];
  __shared__ float sea[32 * 65];
  int4 f = *flg;
  int t = threadIdx.x;
  for (int i = t; i < 512; i += 256) sw[i] = fw[FW_WA12 + i];
  int e0 = blockIdx.x * 32;
  {
    int eloc = t >> 3, kc = (t & 7) * 8;
    float* dp = &sea[eloc * 65 + kc];
    if (f.x){
      const u16* p = (const u16*)ea + (size_t)(e0 + eloc) * 64 + kc;
      ushort4 a = *(const ushort4*)p;
      ushort4 b = *(const ushort4*)(p + 4);
      dp[0] = b2f(a.x); dp[1] = b2f(a.y); dp[2] = b2f(a.z); dp[3] = b2f(a.w);
      dp[4] = b2f(b.x); dp[5] = b2f(b.y); dp[6] = b2f(b.z); dp[7] = b2f(b.w);
    } else {
      const float* p = (const float*)ea + (size_t)(e0 + eloc) * 64 + kc;
      float4 a = *(const float4*)p;
      float4 b = *(const float4*)(p + 4);
      dp[0] = a.x; dp[1] = a.y; dp[2] = a.z; dp[3] = a.w;
      dp[4] = b.x; dp[5] = b.y; dp[6] = b.z; dp[7] = b.w;
    }
  }
  __syncthreads();
  int eloc = t >> 3, d = t & 7;
  int e = e0 + eloc;
  float a = 0.f;
  for (int k = 0; k < 64; k++) a += sea[eloc * 65 + k] * sw[k * 8 + d];
  int et = geti(etype, e, f.w);
  a += (d < 4) ? fw[FW_ETA1 + et * 4 + d] : fw[FW_ETA2 + et * 4 + (d - 4)];
  el[(size_t)e * 8 + d] = a;
}

// ---------------- layer-1 aggregation: ONE WAVE per node, two-pass softmax ----------------
__global__ __launch_bounds__(64) void k_agg1(const int* off, const int4* meta,
    const float* el, const float* s1, const float* d1,
    const void* x, const void* ea, u16* V1, const int4* flg){
  int bf = flg->x;
  int n = blockIdx.x;
  int lane = threadIdx.x;
  int beg = off[n], end = off[n + 1];
  float4 dv = *(const float4*)&d1[n * 4];
  float dvh[4] = {dv.x, dv.y, dv.z, dv.w};

  // pass A: per-head max (lane-redundant, wave-uniform)
  float m[4] = {FNEG, FNEG, FNEG, FNEG};
  for (int i = beg; i < end; i++){
    int4 md = meta[i];
    float4 elv = *(const float4*)&el[(size_t)md.x * 8];
    float4 sv  = *(const float4*)&s1[md.y * 4];
    float lg0 = sv.x + dvh[0] + elv.x; lg0 = fmaxf(lg0, 0.2f * lg0); m[0] = fmaxf(m[0], lg0);
    float lg1 = sv.y + dvh[1] + elv.y; lg1 = fmaxf(lg1, 0.2f * lg1); m[1] = fmaxf(m[1], lg1);
    float lg2 = sv.z + dvh[2] + elv.z; lg2 = fmaxf(lg2, 0.2f * lg2); m[2] = fmaxf(m[2], lg2);
    float lg3 = sv.w + dvh[3] + elv.w; lg3 = fmaxf(lg3, 0.2f * lg3); m[3] = fmaxf(m[3], lg3);
  }

  // pass B: p = exp(l - m); accumulate
  float den[4] = {0.f, 0.f, 0.f, 0.f};
  float g1[4] = {0.f, 0.f, 0.f, 0.f};
  float g2[4] = {0.f, 0.f, 0.f, 0.f};
  float t1 = 0.f, t2a = 0.f, t2b = 0.f;
  for (int i = beg; i < end; i++){
    int4 md = meta[i];
    int eid = md.x, src = md.y, et = md.z, nt = md.w;
    float4 elv = *(const float4*)&el[(size_t)eid * 8];
    float4 sv  = *(const float4*)&s1[src * 4];
    float lg[4] = {sv.x + dvh[0] + elv.x, sv.y + dvh[1] + elv.y,
                   sv.z + dvh[2] + elv.z, sv.w + dvh[3] + elv.w};
    float pa[4];
#pragma unroll
    for (int h = 0; h < 4; h++){
      float l = lg[h]; l = fmaxf(l, 0.2f * l);
      float p = __expf(l - m[h]);
      den[h] += p; pa[h] = p;
    }
    float xv = ldf(x, (size_t)src * 64 + lane, bf);
    float ev = ldf(ea, (size_t)eid * 64 + lane, bf);
#pragma unroll
    for (int h = 0; h < 4; h++){
      float p = pa[h];
      g1[h] += p * xv; g2[h] += p * ev;
      t1  += (lane == h * 8 + nt) ? p : 0.f;
      int s = h * 22 + et;
      t2a += (lane == s)      ? p : 0.f;
      t2b += (lane + 64 == s) ? p : 0.f;
    }
  }
  float inv[4];
#pragma unroll
  for (int h = 0; h < 4; h++)
    inv[h] = (den[h] > 0.f) ? 1.f / (den[h] + 1e-16f) : 0.f;

  u16* vrow = &V1[(size_t)n * K1];
#pragma unroll
  for (int h = 0; h < 4; h++){
    vrow[h * 64 + lane]       = f2b(inv[h] * g1[h]);
    vrow[256 + h * 64 + lane] = f2b(inv[h] * g2[h]);
  }
  if (lane < 32) vrow[512 + lane] = f2b(inv[lane >> 3] * t1);
  vrow[544 + lane] = f2b(inv[lane / 22] * t2a);
  if (lane < 24) vrow[608 + lane] = f2b(inv[(lane + 64) / 22] * t2b);
  vrow[632 + lane] = f2b(ldf(x, (size_t)n * 64 + lane, bf));
  if (lane == 0) vrow[696] = f2b(1.f);
  if (lane >= 1 && lane < 8) vrow[696 + lane] = 0;
}

// ---------------- layer-2 aggregation (node chunk): ONE WAVE per node ----------------
__global__ __launch_bounds__(64) void k_agg2(const int* off, const int4* meta,
    const float* el, const float* s2, const float* d2,
    const u16* hbuf, const void* ea, u16* V2, int nbase, const int4* flg){
  int bf = flg->x;
  int n = nbase + blockIdx.x;
  int lane = threadIdx.x;
  int beg = off[n], end = off[n + 1];
  float4 dv = *(const float4*)&d2[n * 4];
  float dvh[4] = {dv.x, dv.y, dv.z, dv.w};

  float m[4] = {FNEG, FNEG, FNEG, FNEG};
  for (int i = beg; i < end; i++){
    int4 md = meta[i];
    float4 elv = *(const float4*)&el[(size_t)md.x * 8 + 4];
    float4 sv  = *(const float4*)&s2[md.y * 4];
    float lg0 = sv.x + dvh[0] + elv.x; lg0 = fmaxf(lg0, 0.2f * lg0); m[0] = fmaxf(m[0], lg0);
    float lg1 = sv.y + dvh[1] + elv.y; lg1 = fmaxf(lg1, 0.2f * lg1); m[1] = fmaxf(m[1], lg1);
    float lg2 = sv.z + dvh[2] + elv.z; lg2 = fmaxf(lg2, 0.2f * lg2); m[2] = fmaxf(m[2], lg2);
    float lg3 = sv.w + dvh[3] + elv.w; lg3 = fmaxf(lg3, 0.2f * lg3); m[3] = fmaxf(m[3], lg3);
  }

  float den[4] = {0.f, 0.f, 0.f, 0.f};
  float g3[4][4] = {};
  float g4[4] = {0.f, 0.f, 0.f, 0.f};
  float t3 = 0.f, t4a = 0.f, t4b = 0.f;
  for (int i = beg; i < end; i++){
    int4 md = meta[i];
    int eid = md.x, src = md.y, et = md.z, nt = md.w;
    float4 elv = *(const float4*)&el[(size_t)eid * 8 + 4];
    float4 sv  = *(const float4*)&s2[src * 4];
    float lg[4] = {sv.x + dvh[0] + elv.x, sv.y + dvh[1] + elv.y,
                   sv.z + dvh[2] + elv.z, sv.w + dvh[3] + elv.w};
    float pa[4];
#pragma unroll
    for (int h = 0; h < 4; h++){
      float l = lg[h]; l = fmaxf(l, 0.2f * l);
      float p = __expf(l - m[h]);
      den[h] += p; pa[h] = p;
    }
    ushort4 hv = *(const ushort4*)&hbuf[(size_t)src * 256 + lane * 4];
    float h0 = b2f(hv.x), h1 = b2f(hv.y), h2 = b2f(hv.z), h3 = b2f(hv.w);
    float ev = ldf(ea, (size_t)eid * 64 + lane, bf);
#pragma unroll
    for (int h = 0; h < 4; h++){
      float p = pa[h];
      g3[h][0] += p * h0; g3[h][1] += p * h1; g3[h][2] += p * h2; g3[h][3] += p * h3;
      g4[h] += p * ev;
      t3 += (lane == h * 8 + nt) ? p : 0.f;
      int s = h * 22 + et;
      t4a += (lane == s)      ? p : 0.f;
      t4b += (lane + 64 == s) ? p : 0.f;
    }
  }
  float inv[4];
#pragma unroll
  for (int h = 0; h < 4; h++)
    inv[h] = (den[h] > 0.f) ? 1.f / (den[h] + 1e-16f) : 0.f;

  u16* vrow = &V2[(size_t)blockIdx.x * K2V];
#pragma unroll
  for (int h = 0; h < 4; h++){
#pragma unroll
    for (int j = 0; j < 4; j++)
      vrow[h * 256 + lane * 4 + j] = f2b(inv[h] * g3[h][j]);
    vrow[1024 + h * 64 + lane] = f2b(inv[h] * g4[h]);
  }
  if (lane < 32) vrow[1280 + lane] = f2b(inv[lane >> 3] * t3);
  vrow[1312 + lane] = f2b(inv[lane / 22] * t4a);
  if (lane < 24) vrow[1376 + lane] = f2b(inv[(lane + 64) / 22] * t4b);
  if (lane == 0) vrow[1400] = f2b(1.f);
  if (lane >= 1 && lane < 8) vrow[1400 + lane] = 0;
}

// ---------------- simple LDS-tiled vector GEMM: C[rowbase+r,256] = A[r,:]@Bt^T ----------------
// MODE 1: relu -> bf16 hbuf.  MODE 2: + residual -> f32 d_out (reference output dtype!)
template<int KK, int MODE>
__global__ __launch_bounds__(256) void k_sgemm(const u16* A, const u16* Bt,
                                               const u16* hres, void* outv,
                                               int rowbase, int mcount){
  __shared__ float As[16 * 68];
  __shared__ float Bs[16 * 68];
  int t = threadIdx.x;
  int tx = t & 15, ty = t >> 4;
  int m0 = blockIdx.x * 16, n0 = blockIdx.y * 16;
  float acc = 0.f;
  for (int k0 = 0; k0 < KK; k0 += 64){
    for (int q = t; q < 1024; q += 256){
      int row = q >> 6, kk = q & 63;
      int ga = m0 + row;
      As[row * 68 + kk] = (ga < mcount) ? b2f(A[(size_t)ga * KK + k0 + kk]) : 0.f;
      Bs[row * 68 + kk] = b2f(Bt[(size_t)(n0 + row) * KK + k0 + kk]);
    }
    __syncthreads();
    const float4* Ar = (const float4*)&As[ty * 68];
    const float4* Br = (const float4*)&Bs[tx * 68];
#pragma unroll
    for (int k4 = 0; k4 < 16; k4++){
      float4 a = Ar[k4], b = Br[k4];
      acc += a.x * b.x + a.y * b.y + a.z * b.z + a.w * b.w;
    }
    __syncthreads();
  }
  int rowL = m0 + ty, col = n0 + tx;
  if (rowL < mcount){
    int rowG = rowbase + rowL;
    if (MODE == 1){
      float v = fmaxf(acc, 0.f);
      ((u16*)outv)[(size_t)rowG * 256 + col] = f2b(v);
    } else {
      float v = acc + b2f(hres[(size_t)rowG * 256 + col]);
      ((float*)outv)[(size_t)rowG * 256 + col] = v;   // f32 output per reference dtype
    }
  }
}

// ---------------- launcher ----------------
extern "C" void kernel_launch(void* const* d_in, const int* in_sizes, int n_in,
                              void* d_out, int out_size, void* d_ws, size_t ws_size,
                              hipStream_t stream){
  const void* x      = d_in[0];
  const int*  ei     = (const int*)d_in[1];
  const int*  ntype  = (const int*)d_in[2];
  const void* ea     = d_in[3];
  const int*  etype  = (const int*)d_in[4];
  const void* l1_W     = d_in[5];
  const void* l1_b     = d_in[6];
  const void* l1_Wedge = d_in[7];
  const void* l1_ntemb = d_in[8];
  const void* l1_etemb = d_in[9];
  const void* l1_asrc  = d_in[10];
  const void* l1_adst  = d_in[11];
  const void* l1_aedge = d_in[12];
  const void* l1_res   = d_in[13];
  const void* l2_W     = d_in[14];
  const void* l2_b     = d_in[15];
  const void* l2_Wedge = d_in[16];
  const void* l2_ntemb = d_in[17];
  const void* l2_etemb = d_in[18];
  const void* l2_asrc  = d_in[19];
  const void* l2_adst  = d_in[20];
  const void* l2_aedge = d_in[21];

  char* ws = (char*)d_ws;
  int4*  flg    = (int4*)(ws + WS_FLG);
  int*   deg    = (int*)(ws + WS_DEG);
  int*   off    = (int*)(ws + WS_OFF);
  int*   cur    = (int*)(ws + WS_CUR);
  int4*  meta   = (int4*)(ws + WS_META);
  float* el     = (float*)(ws + WS_EL);
  float* s1     = (float*)(ws + WS_S1);
  float* d1     = (float*)(ws + WS_D1);
  float* s2     = (float*)(ws + WS_S2);
  float* d2     = (float*)(ws + WS_D2);
  float* fw     = (float*)(ws + WS_FW);
  u16*   M1T    = (u16*)(ws + WS_M1T);
  u16*   M2T    = (u16*)(ws + WS_M2T);
  u16*   hbuf   = (u16*)(ws + WS_HBUF);
  u16*   V      = (u16*)(ws + WS_V);

  hipLaunchKernelGGL(k_probe,   dim3(1),    dim3(64),  0, stream,
                     (const u16*)x, ei, ntype, etype, flg);
  hipLaunchKernelGGL(k_zero,    dim3(40),   dim3(256), 0, stream, deg);
  hipLaunchKernelGGL(k_hist,    dim3(1250), dim3(256), 0, stream, ei, deg, flg);
  hipLaunchKernelGGL(k_scan,    dim3(1),    dim3(256), 0, stream, deg, off, cur);
  hipLaunchKernelGGL(k_scatter, dim3(1250), dim3(256), 0, stream, ei, ntype, etype, cur, meta, flg);
  hipLaunchKernelGGL(k_fold_a,  dim3(8),    dim3(256), 0, stream,
                     l1_W, l1_Wedge, l1_asrc, l1_adst, l1_aedge, l1_etemb,
                     l2_W, l2_Wedge, l2_asrc, l2_adst, l2_aedge, l2_etemb, fw, flg);
  hipLaunchKernelGGL(k_fold_b,  dim3(1),    dim3(64),  0, stream, l1_ntemb, l2_ntemb, fw, flg);
  hipLaunchKernelGGL(k_m1t,     dim3(256),  dim3(256), 0, stream,
                     l1_W, l1_Wedge, l1_ntemb, l1_etemb, l1_res, l1_b, M1T, flg);
  hipLaunchKernelGGL(k_m2t,     dim3(256),  dim3(256), 0, stream,
                     l2_W, l2_Wedge, l2_ntemb, l2_etemb, l2_b, M2T, flg);
  hipLaunchKernelGGL(k_sd1,     dim3(157),  dim3(256), 0, stream, x, ntype, fw, s1, d1, flg);
  hipLaunchKernelGGL(k_el,      dim3(10000),dim3(256), 0, stream, ea, etype, fw, el, flg);
  hipLaunchKernelGGL(k_agg1,    dim3(10000),dim3(64),  0, stream, off, meta, el, s1, d1, x, ea, V, flg);
  hipLaunchKernelGGL((k_sgemm<K1, 1>),  dim3(625, 16), dim3(256), 0, stream, V, M1T, hbuf, (void*)hbuf, 0, NN);
  hipLaunchKernelGGL(k_sd2,     dim3(157),  dim3(256), 0, stream, hbuf, ntype, fw, s2, d2, flg);
  for (int c = 0; c < 2; c++){
    int base = c * 5000;
    hipLaunchKernelGGL(k_agg2,  dim3(5000), dim3(64),  0, stream,
                       off, meta, el, s2, d2, hbuf, ea, V, base, flg);
    hipLaunchKernelGGL((k_sgemm<K2V, 2>), dim3(313, 16), dim3(256), 0, stream,
                       V, M2T, hbuf, d_out, base, 5000);
  }
}

// Round 6
// 744.071 us; speedup vs baseline: 1.5587x; 1.5587x over previous
//
#include <hip/hip_runtime.h>
#include <stdint.h>

// ---------------- problem constants ----------------
#define NN   10000
#define NE   320000
#define K1   704    // V1 width: 256(G1)+256(G2)+32(T1)+88(T2)+64(x)+1(bias)+7 pad
#define K2V  1408   // V2 width: 1024(G3)+256(G4)+32(T3)+88(T4)+1(bias)+7 pad

#define FNEG (-1.0e30f)

typedef unsigned short u16;
typedef unsigned int   u32;

__device__ __forceinline__ float b2f(u16 v){ u32 u = ((u32)v) << 16; return __uint_as_float(u); }
__device__ __forceinline__ u16 f2b(float f){
  u32 u = __float_as_uint(f);
  u32 r = (u + 0x7fffu + ((u >> 16) & 1u)) >> 16;
  return (u16)r;
}
// dtype-adaptive scalar float load: bf=1 -> bf16 u16, bf=0 -> f32
__device__ __forceinline__ float ldf(const void* p, size_t i, int bf){
  if (bf){ u32 u = ((u32)((const u16*)p)[i]) << 16; return __uint_as_float(u); }
  return ((const float*)p)[i];
}
// width-adaptive int load: w64=1 -> int64 storage (read low word)
__device__ __forceinline__ int geti(const int* p, size_t i, int w64){
  return w64 ? p[2 * i] : p[i];
}

// folded-weight f32 region offsets (floats)
#define FW_W1A  0
#define FW_W1D  256
#define FW_WA12 512
#define FW_ETA1 1024
#define FW_ETA2 1112
#define FW_NTS1 1200
#define FW_NTD1 1232
#define FW_W2A  1264
#define FW_W2D  2288
#define FW_NTS2 3312
#define FW_NTD2 3344

// workspace byte offsets; total = 36,417,376 bytes (~36.4 MB)
#define WS_FLG   0u
#define WS_DEG   16u
#define WS_OFF   40016u
#define WS_CUR   80032u
#define WS_META  120032u
#define WS_EL    5240032u
#define WS_S1    15480032u
#define WS_D1    15640032u
#define WS_S2    15800032u
#define WS_D2    15960032u
#define WS_FW    16120032u
#define WS_M1T   16136032u
#define WS_M2T   16496480u
#define WS_HBUF  17217376u
#define WS_V     22337376u   // 14,080,000 B: V1 (10000x704) or V2 chunk (5000x1408)

// ---------------- runtime dtype/width probe ----------------
__global__ void k_probe(const u16* x16, const int* ei, const int* nt, const int* et, int4* flg){
  if (threadIdx.x == 0 && blockIdx.x == 0){
    int okb = 1;
    for (int i = 0; i < 64; i++){
      u16 u = x16[i]; int e = (u >> 7) & 0xFF;
      if (!(e >= 90 && e <= 160)){ okb = 0; break; }
    }
    int ei64 = 1, nt64 = 1, et64 = 1;
    for (int i = 0; i < 32; i++){
      if (ei[2 * i + 1] != 0) ei64 = 0;
      if (nt[2 * i + 1] != 0) nt64 = 0;
      if (et[2 * i + 1] != 0) et64 = 0;
    }
    int4 f; f.x = okb; f.y = ei64; f.z = nt64; f.w = et64;
    *flg = f;
  }
}

// ---------------- CSR build ----------------
__global__ void k_zero(int* deg){
  int t = blockIdx.x * 256 + threadIdx.x;
  if (t < NN) deg[t] = 0;
}

__global__ void k_hist(const int* ei, int* deg, const int4* flg){
  int4 f = *flg;
  int e = blockIdx.x * 256 + threadIdx.x;
  if (e < NE){ int dst = geti(ei, NE + e, f.y); atomicAdd(&deg[dst], 1); }
}

__global__ void k_scan(const int* deg, int* off, int* cursor){
  __shared__ int part[256];
  int t = threadIdx.x;
  int base = t * 40;
  int s = 0;
  for (int i = 0; i < 40; i++){ int idx = base + i; s += (idx < NN) ? deg[idx] : 0; }
  part[t] = s;
  __syncthreads();
  for (int d = 1; d < 256; d <<= 1){
    int v = (t >= d) ? part[t - d] : 0;
    __syncthreads();
    part[t] += v;
    __syncthreads();
  }
  int run = (t == 0) ? 0 : part[t - 1];
  for (int i = 0; i < 40; i++){
    int idx = base + i;
    if (idx < NN){ off[idx] = run; cursor[idx] = run; run += deg[idx]; }
  }
  if (t == 255) off[NN] = part[255];
}

__global__ void k_scatter(const int* ei, const int* ntype, const int* etype,
                          int* cursor, int4* meta, const int4* flg){
  int4 f = *flg;
  int e = blockIdx.x * 256 + threadIdx.x;
  if (e < NE){
    int src = geti(ei, e, f.y), dst = geti(ei, NE + e, f.y);
    int pos = atomicAdd(&cursor[dst], 1);
    int4 m; m.x = e; m.y = src; m.z = geti(etype, e, f.w); m.w = geti(ntype, src, f.z);
    meta[pos] = m;
  }
}

// ---------------- weight folding ----------------
__global__ void k_fold_a(const void* W1, const void* Wedge1, const void* asrc1, const void* adst1,
                         const void* aedge1, const void* etemb1,
                         const void* W2, const void* Wedge2, const void* asrc2, const void* adst2,
                         const void* aedge2, const void* etemb2, float* fw, const int4* flg){
  int bf = flg->x;
  int s = blockIdx.x * 256 + threadIdx.x;
  if (s < 256){            // W1a / W1d
    int k = s >> 2, h = s & 3; float a = 0.f, d = 0.f;
    for (int c = 0; c < 64; c++){
      float w = ldf(W1, k * 256 + h * 64 + c, bf);
      a += w * ldf(asrc1, h * 64 + c, bf); d += w * ldf(adst1, h * 64 + c, bf);
    }
    fw[FW_W1A + k * 4 + h] = a; fw[FW_W1D + k * 4 + h] = d;
  } else if (s < 768){     // wa12 [64][8]
    int q = s - 256; int k = q >> 3, dd = q & 7; float a = 0.f;
    if (dd < 4){
      for (int c = 0; c < 64; c++) a += ldf(Wedge1, k * 256 + dd * 64 + c, bf) * ldf(aedge1, dd * 64 + c, bf);
    } else {
      int h = dd - 4;
      for (int c = 0; c < 256; c++) a += ldf(Wedge2, k * 1024 + h * 256 + c, bf) * ldf(aedge2, h * 256 + c, bf);
    }
    fw[FW_WA12 + k * 8 + dd] = a;
  } else if (s < 856){     // eta1 [22][4]
    int q = s - 768; int te = q >> 2, h = q & 3; float a = 0.f;
    for (int c = 0; c < 64; c++) a += ldf(etemb1, te * 256 + h * 64 + c, bf) * ldf(aedge1, h * 64 + c, bf);
    fw[FW_ETA1 + te * 4 + h] = a;
  } else if (s < 944){     // eta2 [22][4]
    int q = s - 856; int te = q >> 2, h = q & 3; float a = 0.f;
    for (int c = 0; c < 256; c++) a += ldf(etemb2, te * 1024 + h * 256 + c, bf) * ldf(aedge2, h * 256 + c, bf);
    fw[FW_ETA2 + te * 4 + h] = a;
  } else if (s < 1968){    // W2a / W2d [256][4]
    int q = s - 944; int k = q >> 2, h = q & 3; float a = 0.f, d = 0.f;
    for (int c = 0; c < 256; c++){
      float w = ldf(W2, k * 1024 + h * 256 + c, bf);
      a += w * ldf(asrc2, h * 256 + c, bf); d += w * ldf(adst2, h * 256 + c, bf);
    }
    fw[FW_W2A + k * 4 + h] = a; fw[FW_W2D + k * 4 + h] = d;
  }
}

__global__ void k_fold_b(const void* ntemb1, const void* ntemb2, float* fw, const int4* flg){
  int bf = flg->x;
  int t = threadIdx.x;   // 64 threads
  if (t < 32){
    int te = t >> 2, h = t & 3; float a = 0.f, d = 0.f;
    for (int k = 0; k < 64; k++){
      float x = ldf(ntemb1, te * 64 + k, bf);
      a += x * fw[FW_W1A + k * 4 + h]; d += x * fw[FW_W1D + k * 4 + h];
    }
    fw[FW_NTS1 + te * 4 + h] = a; fw[FW_NTD1 + te * 4 + h] = d;
  } else {
    int q = t - 32; int te = q >> 2, h = q & 3; float a = 0.f, d = 0.f;
    for (int k = 0; k < 256; k++){
      float x = ldf(ntemb2, te * 256 + k, bf);
      a += x * fw[FW_W2A + k * 4 + h]; d += x * fw[FW_W2D + k * 4 + h];
    }
    fw[FW_NTS2 + te * 4 + h] = a; fw[FW_NTD2 + te * 4 + h] = d;
  }
}

// ---------------- combined-weight matrices (stored transposed: [col][row]) ----------------
__global__ void k_m1t(const void* W1, const void* Wedge1, const void* ntemb1, const void* etemb1,
                      const void* res1, const void* b1, u16* M1T, const int4* flg){
  int bf = flg->x;
  int c = blockIdx.x; int t = threadIdx.x; int ch = c >> 6;
  for (int r = t; r < K1; r += 256){
    float v = 0.f;
    if (r < 256){ int h = r >> 6, k = r & 63; v = (h == ch) ? ldf(W1, k * 256 + c, bf) : 0.f; }
    else if (r < 512){ int q = r - 256; int h = q >> 6, k = q & 63; v = (h == ch) ? ldf(Wedge1, k * 256 + c, bf) : 0.f; }
    else if (r < 544){ int q = r - 512; int h = q >> 3, te = q & 7;
      if (h == ch){ float a = 0.f; for (int k = 0; k < 64; k++) a += ldf(ntemb1, te * 64 + k, bf) * ldf(W1, k * 256 + c, bf); v = a; } }
    else if (r < 632){ int q = r - 544; int h = q / 22, te = q % 22; v = (h == ch) ? ldf(etemb1, te * 256 + c, bf) : 0.f; }
    else if (r < 696){ int k = r - 632; v = ldf(res1, k * 256 + c, bf); }
    else if (r == 696){ v = ldf(b1, c, bf); }
    M1T[c * K1 + r] = f2b(v);
  }
}

__global__ void k_m2t(const void* W2, const void* Wedge2, const void* ntemb2, const void* etemb2,
                      const void* b2, u16* M2T, const int4* flg){
  int bf = flg->x;
  int c = blockIdx.x; int t = threadIdx.x;
  for (int r = t; r < K2V; r += 256){
    float v = 0.f;
    if (r < 1024){ int h = r >> 8, k = r & 255; v = 0.25f * ldf(W2, k * 1024 + h * 256 + c, bf); }
    else if (r < 1280){ int q = r - 1024; int h = q >> 6, k = q & 63; v = 0.25f * ldf(Wedge2, k * 1024 + h * 256 + c, bf); }
    else if (r < 1312){ int q = r - 1280; int h = q >> 3, te = q & 7; float a = 0.f;
      for (int k = 0; k < 256; k++) a += ldf(ntemb2, te * 256 + k, bf) * ldf(W2, k * 1024 + h * 256 + c, bf);
      v = 0.25f * a; }
    else if (r < 1400){ int q = r - 1312; int h = q / 22, te = q % 22; v = 0.25f * ldf(etemb2, te * 1024 + h * 256 + c, bf); }
    else if (r == 1400){ v = ldf(b2, c, bf); }
    M2T[c * K2V + r] = f2b(v);
  }
}

// ---------------- per-node attention scalars ----------------
__global__ void k_sd1(const void* x, const int* ntype, const float* fw, float* s1, float* d1,
                      const int4* flg){
  int4 f = *flg;
  int id = blockIdx.x * 256 + threadIdx.x;
  if (id >= NN * 4) return;
  int n = id >> 2, h = id & 3;
  float a = 0.f, d = 0.f;
  for (int k = 0; k < 64; k++){
    float xv = ldf(x, (size_t)n * 64 + k, f.x);
    a += xv * fw[FW_W1A + k * 4 + h]; d += xv * fw[FW_W1D + k * 4 + h];
  }
  int nt = geti(ntype, n, f.z);
  s1[id] = a + fw[FW_NTS1 + nt * 4 + h];
  d1[id] = d + fw[FW_NTD1 + nt * 4 + h];
}

__global__ void k_sd2(const u16* hbuf, const int* ntype, const float* fw, float* s2, float* d2,
                      const int4* flg){
  int4 f = *flg;
  int id = blockIdx.x * 256 + threadIdx.x;
  if (id >= NN * 4) return;
  int n = id >> 2, h = id & 3;
  float a = 0.f, d = 0.f;
  for (int k = 0; k < 256; k++){
    float xv = b2f(hbuf[n * 256 + k]);
    a += xv * fw[FW_W2A + k * 4 + h]; d += xv * fw[FW_W2D + k * 4 + h];
  }
  int nt = geti(ntype, n, f.z);
  s2[id] = a + fw[FW_NTS2 + nt * 4 + h];
  d2[id] = d + fw[FW_NTD2 + nt * 4 + h];
}

// ---------------- edge attention-logit contributions (both layers) ----------------
__global__ void k_el(const void* ea, const int* etype, const float* fw, float* el, const int4* flg){
  __shared__ float sw[512];
  __shared__ float sea[32 * 65];
  int4 f = *flg;
  int t = threadIdx.x;
  for (int i = t; i < 512; i += 256) sw[i] = fw[FW_WA12 + i];
  int e0 = blockIdx.x * 32;
  {
    int eloc = t >> 3, kc = (t & 7) * 8;
    float* dp = &sea[eloc * 65 + kc];
    if (f.x){
      const u16* p = (const u16*)ea + (size_t)(e0 + eloc) * 64 + kc;
      ushort4 a = *(const ushort4*)p;
      ushort4 b = *(const ushort4*)(p + 4);
      dp[0] = b2f(a.x); dp[1] = b2f(a.y); dp[2] = b2f(a.z); dp[3] = b2f(a.w);
      dp[4] = b2f(b.x); dp[5] = b2f(b.y); dp[6] = b2f(b.z); dp[7] = b2f(b.w);
    } else {
      const float* p = (const float*)ea + (size_t)(e0 + eloc) * 64 + kc;
      float4 a = *(const float4*)p;
      float4 b = *(const float4*)(p + 4);
      dp[0] = a.x; dp[1] = a.y; dp[2] = a.z; dp[3] = a.w;
      dp[4] = b.x; dp[5] = b.y; dp[6] = b.z; dp[7] = b.w;
    }
  }
  __syncthreads();
  int eloc = t >> 3, d = t & 7;
  int e = e0 + eloc;
  float a = 0.f;
  for (int k = 0; k < 64; k++) a += sea[eloc * 65 + k] * sw[k * 8 + d];
  int et = geti(etype, e, f.w);
  a += (d < 4) ? fw[FW_ETA1 + et * 4 + d] : fw[FW_ETA2 + et * 4 + (d - 4)];
  el[(size_t)e * 8 + d] = a;
}

// ---------------- layer-1 aggregation: one wave per node, 4 nodes/block ----------------
__global__ __launch_bounds__(256) void k_agg1(const int* off, const int4* meta,
    const float* el, const float* s1, const float* d1,
    const void* x, const void* ea, u16* V1, const int4* flg){
  int bf = flg->x;
  int n = blockIdx.x * 4 + (threadIdx.x >> 6);
  int lane = threadIdx.x & 63;
  int beg = off[n], end = off[n + 1];
  float4 dv = *(const float4*)&d1[n * 4];
  float dvh[4] = {dv.x, dv.y, dv.z, dv.w};

  // pass A: per-head max (lane-redundant, wave-uniform)
  float m[4] = {FNEG, FNEG, FNEG, FNEG};
  for (int i = beg; i < end; i++){
    int4 md = meta[i];
    float4 elv = *(const float4*)&el[(size_t)md.x * 8];
    float4 sv  = *(const float4*)&s1[md.y * 4];
    float lg0 = sv.x + dvh[0] + elv.x; lg0 = fmaxf(lg0, 0.2f * lg0); m[0] = fmaxf(m[0], lg0);
    float lg1 = sv.y + dvh[1] + elv.y; lg1 = fmaxf(lg1, 0.2f * lg1); m[1] = fmaxf(m[1], lg1);
    float lg2 = sv.z + dvh[2] + elv.z; lg2 = fmaxf(lg2, 0.2f * lg2); m[2] = fmaxf(m[2], lg2);
    float lg3 = sv.w + dvh[3] + elv.w; lg3 = fmaxf(lg3, 0.2f * lg3); m[3] = fmaxf(m[3], lg3);
  }

  // pass B: p = exp(l - m); accumulate
  float den[4] = {0.f, 0.f, 0.f, 0.f};
  float g1[4] = {0.f, 0.f, 0.f, 0.f};
  float g2[4] = {0.f, 0.f, 0.f, 0.f};
  float t1 = 0.f, t2a = 0.f, t2b = 0.f;
  for (int i = beg; i < end; i++){
    int4 md = meta[i];
    int eid = md.x, src = md.y, et = md.z, nt = md.w;
    float4 elv = *(const float4*)&el[(size_t)eid * 8];
    float4 sv  = *(const float4*)&s1[src * 4];
    float lg[4] = {sv.x + dvh[0] + elv.x, sv.y + dvh[1] + elv.y,
                   sv.z + dvh[2] + elv.z, sv.w + dvh[3] + elv.w};
    float pa[4];
#pragma unroll
    for (int h = 0; h < 4; h++){
      float l = lg[h]; l = fmaxf(l, 0.2f * l);
      float p = __expf(l - m[h]);
      den[h] += p; pa[h] = p;
    }
    float xv = ldf(x, (size_t)src * 64 + lane, bf);
    float ev = ldf(ea, (size_t)eid * 64 + lane, bf);
#pragma unroll
    for (int h = 0; h < 4; h++){
      float p = pa[h];
      g1[h] += p * xv; g2[h] += p * ev;
      t1  += (lane == h * 8 + nt) ? p : 0.f;
      int s = h * 22 + et;
      t2a += (lane == s)      ? p : 0.f;
      t2b += (lane + 64 == s) ? p : 0.f;
    }
  }
  float inv[4];
#pragma unroll
  for (int h = 0; h < 4; h++)
    inv[h] = (den[h] > 0.f) ? 1.f / (den[h] + 1e-16f) : 0.f;

  u16* vrow = &V1[(size_t)n * K1];
#pragma unroll
  for (int h = 0; h < 4; h++){
    vrow[h * 64 + lane]       = f2b(inv[h] * g1[h]);
    vrow[256 + h * 64 + lane] = f2b(inv[h] * g2[h]);
  }
  if (lane < 32) vrow[512 + lane] = f2b(inv[lane >> 3] * t1);
  vrow[544 + lane] = f2b(inv[lane / 22] * t2a);
  if (lane < 24) vrow[608 + lane] = f2b(inv[(lane + 64) / 22] * t2b);
  vrow[632 + lane] = f2b(ldf(x, (size_t)n * 64 + lane, bf));
  if (lane == 0) vrow[696] = f2b(1.f);
  if (lane >= 1 && lane < 8) vrow[696 + lane] = 0;
}

// ---------------- layer-2 aggregation (node chunk): one wave per node, 4/block ----------------
__global__ __launch_bounds__(256) void k_agg2(const int* off, const int4* meta,
    const float* el, const float* s2, const float* d2,
    const u16* hbuf, const void* ea, u16* V2, int nbase, const int4* flg){
  int bf = flg->x;
  int nl = blockIdx.x * 4 + (threadIdx.x >> 6);
  int n = nbase + nl;
  int lane = threadIdx.x & 63;
  int beg = off[n], end = off[n + 1];
  float4 dv = *(const float4*)&d2[n * 4];
  float dvh[4] = {dv.x, dv.y, dv.z, dv.w};

  float m[4] = {FNEG, FNEG, FNEG, FNEG};
  for (int i = beg; i < end; i++){
    int4 md = meta[i];
    float4 elv = *(const float4*)&el[(size_t)md.x * 8 + 4];
    float4 sv  = *(const float4*)&s2[md.y * 4];
    float lg0 = sv.x + dvh[0] + elv.x; lg0 = fmaxf(lg0, 0.2f * lg0); m[0] = fmaxf(m[0], lg0);
    float lg1 = sv.y + dvh[1] + elv.y; lg1 = fmaxf(lg1, 0.2f * lg1); m[1] = fmaxf(m[1], lg1);
    float lg2 = sv.z + dvh[2] + elv.z; lg2 = fmaxf(lg2, 0.2f * lg2); m[2] = fmaxf(m[2], lg2);
    float lg3 = sv.w + dvh[3] + elv.w; lg3 = fmaxf(lg3, 0.2f * lg3); m[3] = fmaxf(m[3], lg3);
  }

  float den[4] = {0.f, 0.f, 0.f, 0.f};
  float g3[4][4] = {};
  float g4[4] = {0.f, 0.f, 0.f, 0.f};
  float t3 = 0.f, t4a = 0.f, t4b = 0.f;
  for (int i = beg; i < end; i++){
    int4 md = meta[i];
    int eid = md.x, src = md.y, et = md.z, nt = md.w;
    float4 elv = *(const float4*)&el[(size_t)eid * 8 + 4];
    float4 sv  = *(const float4*)&s2[src * 4];
    float lg[4] = {sv.x + dvh[0] + elv.x, sv.y + dvh[1] + elv.y,
                   sv.z + dvh[2] + elv.z, sv.w + dvh[3] + elv.w};
    float pa[4];
#pragma unroll
    for (int h = 0; h < 4; h++){
      float l = lg[h]; l = fmaxf(l, 0.2f * l);
      float p = __expf(l - m[h]);
      den[h] += p; pa[h] = p;
    }
    ushort4 hv = *(const ushort4*)&hbuf[(size_t)src * 256 + lane * 4];
    float h0 = b2f(hv.x), h1 = b2f(hv.y), h2 = b2f(hv.z), h3 = b2f(hv.w);
    float ev = ldf(ea, (size_t)eid * 64 + lane, bf);
#pragma unroll
    for (int h = 0; h < 4; h++){
      float p = pa[h];
      g3[h][0] += p * h0; g3[h][1] += p * h1; g3[h][2] += p * h2; g3[h][3] += p * h3;
      g4[h] += p * ev;
      t3 += (lane == h * 8 + nt) ? p : 0.f;
      int s = h * 22 + et;
      t4a += (lane == s)      ? p : 0.f;
      t4b += (lane + 64 == s) ? p : 0.f;
    }
  }
  float inv[4];
#pragma unroll
  for (int h = 0; h < 4; h++)
    inv[h] = (den[h] > 0.f) ? 1.f / (den[h] + 1e-16f) : 0.f;

  u16* vrow = &V2[(size_t)nl * K2V];
#pragma unroll
  for (int h = 0; h < 4; h++){
#pragma unroll
    for (int j = 0; j < 4; j++)
      vrow[h * 256 + lane * 4 + j] = f2b(inv[h] * g3[h][j]);
    vrow[1024 + h * 64 + lane] = f2b(inv[h] * g4[h]);
  }
  if (lane < 32) vrow[1280 + lane] = f2b(inv[lane >> 3] * t3);
  vrow[1312 + lane] = f2b(inv[lane / 22] * t4a);
  if (lane < 24) vrow[1376 + lane] = f2b(inv[(lane + 64) / 22] * t4b);
  if (lane == 0) vrow[1400] = f2b(1.f);
  if (lane >= 1 && lane < 8) vrow[1400 + lane] = 0;
}

// ---------------- MFMA GEMM: C[rowbase+r,256] = A[r,:KK] @ Bt^T, fused epilogue ----------------
// MODE 1: relu -> bf16 hbuf.  MODE 2: + residual(hres) -> f32 out
typedef __bf16 bf16x8 __attribute__((ext_vector_type(8)));
typedef float  f32x4  __attribute__((ext_vector_type(4)));

template<int KK, int MODE>
__global__ __launch_bounds__(256) void k_gemm(const u16* A, const u16* Bt,
                                              const u16* hres, void* outv,
                                              int rowbase, int mcount){
  __shared__ __align__(16) u16 As[64 * 40];
  __shared__ __align__(16) u16 Bs[64 * 40];
  int t = threadIdx.x;
  int w = t >> 6, lane = t & 63;
  int m0 = blockIdx.x * 64, n0 = blockIdx.y * 64;
  int wm = w & 1, wn = w >> 1;
  f32x4 acc[2][2] = {};
  int ar = t >> 2, akc = (t & 3) * 8;
  for (int k0 = 0; k0 < KK; k0 += 32){
    {
      int row = m0 + ar;
      ushort4 v0 = {0, 0, 0, 0}, v1 = {0, 0, 0, 0};
      if (row < mcount){
        const u16* p = &A[(size_t)row * KK + k0 + akc];
        v0 = *(const ushort4*)p; v1 = *(const ushort4*)(p + 4);
      }
      *(ushort4*)&As[ar * 40 + akc] = v0;
      *(ushort4*)&As[ar * 40 + akc + 4] = v1;
      const u16* q = &Bt[(size_t)(n0 + ar) * KK + k0 + akc];
      ushort4 b0 = *(const ushort4*)q;
      ushort4 b1 = *(const ushort4*)(q + 4);
      *(ushort4*)&Bs[ar * 40 + akc] = b0;
      *(ushort4*)&Bs[ar * 40 + akc + 4] = b1;
    }
    __syncthreads();
    int kq = (lane >> 4) * 8;
    int ml = lane & 15;
    bf16x8 a0 = *(const bf16x8*)&As[(wm * 32 + ml) * 40 + kq];
    bf16x8 a1 = *(const bf16x8*)&As[(wm * 32 + 16 + ml) * 40 + kq];
    bf16x8 b0 = *(const bf16x8*)&Bs[(wn * 32 + ml) * 40 + kq];
    bf16x8 b1 = *(const bf16x8*)&Bs[(wn * 32 + 16 + ml) * 40 + kq];
    acc[0][0] = __builtin_amdgcn_mfma_f32_16x16x32_bf16(a0, b0, acc[0][0], 0, 0, 0);
    acc[0][1] = __builtin_amdgcn_mfma_f32_16x16x32_bf16(a0, b1, acc[0][1], 0, 0, 0);
    acc[1][0] = __builtin_amdgcn_mfma_f32_16x16x32_bf16(a1, b0, acc[1][0], 0, 0, 0);
    acc[1][1] = __builtin_amdgcn_mfma_f32_16x16x32_bf16(a1, b1, acc[1][1], 0, 0, 0);
    __syncthreads();
  }
  int quad = lane >> 4, col4 = lane & 15;
#pragma unroll
  for (int i = 0; i < 2; i++)
#pragma unroll
    for (int j = 0; j < 2; j++){
      int colG = n0 + wn * 32 + j * 16 + col4;
#pragma unroll
      for (int r = 0; r < 4; r++){
        int rowL = m0 + wm * 32 + i * 16 + quad * 4 + r;
        if (rowL < mcount){
          int rowG = rowbase + rowL;
          float v = acc[i][j][r];
          if (MODE == 1){
            v = fmaxf(v, 0.f);
            ((u16*)outv)[(size_t)rowG * 256 + colG] = f2b(v);
          } else {
            v += b2f(hres[(size_t)rowG * 256 + colG]);
            ((float*)outv)[(size_t)rowG * 256 + colG] = v;   // f32 output per reference dtype
          }
        }
      }
    }
}

// ---------------- launcher ----------------
extern "C" void kernel_launch(void* const* d_in, const int* in_sizes, int n_in,
                              void* d_out, int out_size, void* d_ws, size_t ws_size,
                              hipStream_t stream){
  const void* x      = d_in[0];
  const int*  ei     = (const int*)d_in[1];
  const int*  ntype  = (const int*)d_in[2];
  const void* ea     = d_in[3];
  const int*  etype  = (const int*)d_in[4];
  const void* l1_W     = d_in[5];
  const void* l1_b     = d_in[6];
  const void* l1_Wedge = d_in[7];
  const void* l1_ntemb = d_in[8];
  const void* l1_etemb = d_in[9];
  const void* l1_asrc  = d_in[10];
  const void* l1_adst  = d_in[11];
  const void* l1_aedge = d_in[12];
  const void* l1_res   = d_in[13];
  const void* l2_W     = d_in[14];
  const void* l2_b     = d_in[15];
  const void* l2_Wedge = d_in[16];
  const void* l2_ntemb = d_in[17];
  const void* l2_etemb = d_in[18];
  const void* l2_asrc  = d_in[19];
  const void* l2_adst  = d_in[20];
  const void* l2_aedge = d_in[21];

  char* ws = (char*)d_ws;
  int4*  flg    = (int4*)(ws + WS_FLG);
  int*   deg    = (int*)(ws + WS_DEG);
  int*   off    = (int*)(ws + WS_OFF);
  int*   cur    = (int*)(ws + WS_CUR);
  int4*  meta   = (int4*)(ws + WS_META);
  float* el     = (float*)(ws + WS_EL);
  float* s1     = (float*)(ws + WS_S1);
  float* d1     = (float*)(ws + WS_D1);
  float* s2     = (float*)(ws + WS_S2);
  float* d2     = (float*)(ws + WS_D2);
  float* fw     = (float*)(ws + WS_FW);
  u16*   M1T    = (u16*)(ws + WS_M1T);
  u16*   M2T    = (u16*)(ws + WS_M2T);
  u16*   hbuf   = (u16*)(ws + WS_HBUF);
  u16*   V      = (u16*)(ws + WS_V);

  hipLaunchKernelGGL(k_probe,   dim3(1),    dim3(64),  0, stream,
                     (const u16*)x, ei, ntype, etype, flg);
  hipLaunchKernelGGL(k_zero,    dim3(40),   dim3(256), 0, stream, deg);
  hipLaunchKernelGGL(k_hist,    dim3(1250), dim3(256), 0, stream, ei, deg, flg);
  hipLaunchKernelGGL(k_scan,    dim3(1),    dim3(256), 0, stream, deg, off, cur);
  hipLaunchKernelGGL(k_scatter, dim3(1250), dim3(256), 0, stream, ei, ntype, etype, cur, meta, flg);
  hipLaunchKernelGGL(k_fold_a,  dim3(8),    dim3(256), 0, stream,
                     l1_W, l1_Wedge, l1_asrc, l1_adst, l1_aedge, l1_etemb,
                     l2_W, l2_Wedge, l2_asrc, l2_adst, l2_aedge, l2_etemb, fw, flg);
  hipLaunchKernelGGL(k_fold_b,  dim3(1),    dim3(64),  0, stream, l1_ntemb, l2_ntemb, fw, flg);
  hipLaunchKernelGGL(k_m1t,     dim3(256),  dim3(256), 0, stream,
                     l1_W, l1_Wedge, l1_ntemb, l1_etemb, l1_res, l1_b, M1T, flg);
  hipLaunchKernelGGL(k_m2t,     dim3(256),  dim3(256), 0, stream,
                     l2_W, l2_Wedge, l2_ntemb, l2_etemb, l2_b, M2T, flg);
  hipLaunchKernelGGL(k_sd1,     dim3(157),  dim3(256), 0, stream, x, ntype, fw, s1, d1, flg);
  hipLaunchKernelGGL(k_el,      dim3(10000),dim3(256), 0, stream, ea, etype, fw, el, flg);
  hipLaunchKernelGGL(k_agg1,    dim3(2500), dim3(256), 0, stream, off, meta, el, s1, d1, x, ea, V, flg);
  hipLaunchKernelGGL((k_gemm<K1, 1>),  dim3(157, 4), dim3(256), 0, stream, V, M1T, hbuf, (void*)hbuf, 0, NN);
  hipLaunchKernelGGL(k_sd2,     dim3(157),  dim3(256), 0, stream, hbuf, ntype, fw, s2, d2, flg);
  for (int c = 0; c < 2; c++){
    int base = c * 5000;
    hipLaunchKernelGGL(k_agg2,  dim3(1250), dim3(256), 0, stream,
                       off, meta, el, s2, d2, hbuf, ea, V, base, flg);
    hipLaunchKernelGGL((k_gemm<K2V, 2>), dim3(79, 4), dim3(256), 0, stream,
                       V, M2T, hbuf, d_out, base, 5000);
  }
}

// Round 7
// 605.963 us; speedup vs baseline: 1.9140x; 1.2279x over previous
//
#include <hip/hip_runtime.h>
#include <stdint.h>

// ---------------- problem constants ----------------
#define NN   10000
#define NE   320000
#define K1   704    // V1 width: 256(G1)+256(G2)+32(T1)+88(T2)+64(x)+1(bias)+7 pad
#define K2V  1408   // V2 width: 1024(G3)+256(G4)+32(T3)+88(T4)+1(bias)+7 pad

typedef unsigned short u16;
typedef unsigned int   u32;

__device__ __forceinline__ float b2f(u16 v){ u32 u = ((u32)v) << 16; return __uint_as_float(u); }
__device__ __forceinline__ u16 f2b(float f){
  u32 u = __float_as_uint(f);
  u32 r = (u + 0x7fffu + ((u >> 16) & 1u)) >> 16;
  return (u16)r;
}
// dtype-adaptive scalar float load: bf=1 -> bf16 u16, bf=0 -> f32
__device__ __forceinline__ float ldf(const void* p, size_t i, int bf){
  if (bf){ u32 u = ((u32)((const u16*)p)[i]) << 16; return __uint_as_float(u); }
  return ((const float*)p)[i];
}
// width-adaptive int load: w64=1 -> int64 storage (read low word)
__device__ __forceinline__ int geti(const int* p, size_t i, int w64){
  return w64 ? p[2 * i] : p[i];
}

// folded-weight f32 region offsets (floats)
#define FW_W1A  0
#define FW_W1D  256
#define FW_WA12 512
#define FW_ETA1 1024
#define FW_ETA2 1112
#define FW_NTS1 1200
#define FW_NTD1 1232
#define FW_W2A  1264
#define FW_W2D  2288
#define FW_NTS2 3312
#define FW_NTD2 3344

// workspace byte offsets; total = 36,417,376 bytes (~36.4 MB)
#define WS_FLG   0u
#define WS_DEG   16u
#define WS_OFF   40016u
#define WS_CUR   80032u
#define WS_META  120032u
#define WS_EL    5240032u
#define WS_S1    15480032u
#define WS_D1    15640032u
#define WS_S2    15800032u
#define WS_D2    15960032u
#define WS_FW    16120032u
#define WS_M1T   16136032u
#define WS_M2T   16496480u
#define WS_HBUF  17217376u
#define WS_V     22337376u   // 14,080,000 B: V1 (10000x704) or V2 chunk (5000x1408)

// ---------------- runtime dtype/width probe ----------------
__global__ void k_probe(const u16* x16, const int* ei, const int* nt, const int* et, int4* flg){
  if (threadIdx.x == 0 && blockIdx.x == 0){
    int okb = 1;
    for (int i = 0; i < 64; i++){
      u16 u = x16[i]; int e = (u >> 7) & 0xFF;
      if (!(e >= 90 && e <= 160)){ okb = 0; break; }
    }
    int ei64 = 1, nt64 = 1, et64 = 1;
    for (int i = 0; i < 32; i++){
      if (ei[2 * i + 1] != 0) ei64 = 0;
      if (nt[2 * i + 1] != 0) nt64 = 0;
      if (et[2 * i + 1] != 0) et64 = 0;
    }
    int4 f; f.x = okb; f.y = ei64; f.z = nt64; f.w = et64;
    *flg = f;
  }
}

// ---------------- CSR build ----------------
__global__ void k_zero(int* deg){
  int t = blockIdx.x * 256 + threadIdx.x;
  if (t < NN) deg[t] = 0;
}

__global__ void k_hist(const int* ei, int* deg, const int4* flg){
  int4 f = *flg;
  int e = blockIdx.x * 256 + threadIdx.x;
  if (e < NE){ int dst = geti(ei, NE + e, f.y); atomicAdd(&deg[dst], 1); }
}

__global__ void k_scan(const int* deg, int* off, int* cursor){
  __shared__ int part[256];
  int t = threadIdx.x;
  int base = t * 40;
  int s = 0;
  for (int i = 0; i < 40; i++){ int idx = base + i; s += (idx < NN) ? deg[idx] : 0; }
  part[t] = s;
  __syncthreads();
  for (int d = 1; d < 256; d <<= 1){
    int v = (t >= d) ? part[t - d] : 0;
    __syncthreads();
    part[t] += v;
    __syncthreads();
  }
  int run = (t == 0) ? 0 : part[t - 1];
  for (int i = 0; i < 40; i++){
    int idx = base + i;
    if (idx < NN){ off[idx] = run; cursor[idx] = run; run += deg[idx]; }
  }
  if (t == 255) off[NN] = part[255];
}

__global__ void k_scatter(const int* ei, const int* ntype, const int* etype,
                          int* cursor, int4* meta, const int4* flg){
  int4 f = *flg;
  int e = blockIdx.x * 256 + threadIdx.x;
  if (e < NE){
    int src = geti(ei, e, f.y), dst = geti(ei, NE + e, f.y);
    int pos = atomicAdd(&cursor[dst], 1);
    int4 m; m.x = e; m.y = src; m.z = geti(etype, e, f.w); m.w = geti(ntype, src, f.z);
    meta[pos] = m;
  }
}

// ---------------- weight folding ----------------
__global__ void k_fold_a(const void* W1, const void* Wedge1, const void* asrc1, const void* adst1,
                         const void* aedge1, const void* etemb1,
                         const void* W2, const void* Wedge2, const void* asrc2, const void* adst2,
                         const void* aedge2, const void* etemb2, float* fw, const int4* flg){
  int bf = flg->x;
  int s = blockIdx.x * 256 + threadIdx.x;
  if (s < 256){            // W1a / W1d
    int k = s >> 2, h = s & 3; float a = 0.f, d = 0.f;
    for (int c = 0; c < 64; c++){
      float w = ldf(W1, k * 256 + h * 64 + c, bf);
      a += w * ldf(asrc1, h * 64 + c, bf); d += w * ldf(adst1, h * 64 + c, bf);
    }
    fw[FW_W1A + k * 4 + h] = a; fw[FW_W1D + k * 4 + h] = d;
  } else if (s < 768){     // wa12 [64][8]
    int q = s - 256; int k = q >> 3, dd = q & 7; float a = 0.f;
    if (dd < 4){
      for (int c = 0; c < 64; c++) a += ldf(Wedge1, k * 256 + dd * 64 + c, bf) * ldf(aedge1, dd * 64 + c, bf);
    } else {
      int h = dd - 4;
      for (int c = 0; c < 256; c++) a += ldf(Wedge2, k * 1024 + h * 256 + c, bf) * ldf(aedge2, h * 256 + c, bf);
    }
    fw[FW_WA12 + k * 8 + dd] = a;
  } else if (s < 856){     // eta1 [22][4]
    int q = s - 768; int te = q >> 2, h = q & 3; float a = 0.f;
    for (int c = 0; c < 64; c++) a += ldf(etemb1, te * 256 + h * 64 + c, bf) * ldf(aedge1, h * 64 + c, bf);
    fw[FW_ETA1 + te * 4 + h] = a;
  } else if (s < 944){     // eta2 [22][4]
    int q = s - 856; int te = q >> 2, h = q & 3; float a = 0.f;
    for (int c = 0; c < 256; c++) a += ldf(etemb2, te * 1024 + h * 256 + c, bf) * ldf(aedge2, h * 256 + c, bf);
    fw[FW_ETA2 + te * 4 + h] = a;
  } else if (s < 1968){    // W2a / W2d [256][4]
    int q = s - 944; int k = q >> 2, h = q & 3; float a = 0.f, d = 0.f;
    for (int c = 0; c < 256; c++){
      float w = ldf(W2, k * 1024 + h * 256 + c, bf);
      a += w * ldf(asrc2, h * 256 + c, bf); d += w * ldf(adst2, h * 256 + c, bf);
    }
    fw[FW_W2A + k * 4 + h] = a; fw[FW_W2D + k * 4 + h] = d;
  }
}

__global__ void k_fold_b(const void* ntemb1, const void* ntemb2, float* fw, const int4* flg){
  int bf = flg->x;
  int t = threadIdx.x;   // 64 threads
  if (t < 32){
    int te = t >> 2, h = t & 3; float a = 0.f, d = 0.f;
    for (int k = 0; k < 64; k++){
      float x = ldf(ntemb1, te * 64 + k, bf);
      a += x * fw[FW_W1A + k * 4 + h]; d += x * fw[FW_W1D + k * 4 + h];
    }
    fw[FW_NTS1 + te * 4 + h] = a; fw[FW_NTD1 + te * 4 + h] = d;
  } else {
    int q = t - 32; int te = q >> 2, h = q & 3; float a = 0.f, d = 0.f;
    for (int k = 0; k < 256; k++){
      float x = ldf(ntemb2, te * 256 + k, bf);
      a += x * fw[FW_W2A + k * 4 + h]; d += x * fw[FW_W2D + k * 4 + h];
    }
    fw[FW_NTS2 + te * 4 + h] = a; fw[FW_NTD2 + te * 4 + h] = d;
  }
}

// ---------------- combined-weight matrices (stored transposed: [col][row]) ----------------
__global__ void k_m1t(const void* W1, const void* Wedge1, const void* ntemb1, const void* etemb1,
                      const void* res1, const void* b1, u16* M1T, const int4* flg){
  int bf = flg->x;
  int c = blockIdx.x; int t = threadIdx.x; int ch = c >> 6;
  for (int r = t; r < K1; r += 256){
    float v = 0.f;
    if (r < 256){ int h = r >> 6, k = r & 63; v = (h == ch) ? ldf(W1, k * 256 + c, bf) : 0.f; }
    else if (r < 512){ int q = r - 256; int h = q >> 6, k = q & 63; v = (h == ch) ? ldf(Wedge1, k * 256 + c, bf) : 0.f; }
    else if (r < 544){ int q = r - 512; int h = q >> 3, te = q & 7;
      if (h == ch){ float a = 0.f; for (int k = 0; k < 64; k++) a += ldf(ntemb1, te * 64 + k, bf) * ldf(W1, k * 256 + c, bf); v = a; } }
    else if (r < 632){ int q = r - 544; int h = q / 22, te = q % 22; v = (h == ch) ? ldf(etemb1, te * 256 + c, bf) : 0.f; }
    else if (r < 696){ int k = r - 632; v = ldf(res1, k * 256 + c, bf); }
    else if (r == 696){ v = ldf(b1, c, bf); }
    M1T[c * K1 + r] = f2b(v);
  }
}

__global__ void k_m2t(const void* W2, const void* Wedge2, const void* ntemb2, const void* etemb2,
                      const void* b2, u16* M2T, const int4* flg){
  int bf = flg->x;
  int c = blockIdx.x; int t = threadIdx.x;
  for (int r = t; r < K2V; r += 256){
    float v = 0.f;
    if (r < 1024){ int h = r >> 8, k = r & 255; v = 0.25f * ldf(W2, k * 1024 + h * 256 + c, bf); }
    else if (r < 1280){ int q = r - 1024; int h = q >> 6, k = q & 63; v = 0.25f * ldf(Wedge2, k * 1024 + h * 256 + c, bf); }
    else if (r < 1312){ int q = r - 1280; int h = q >> 3, te = q & 7; float a = 0.f;
      for (int k = 0; k < 256; k++) a += ldf(ntemb2, te * 256 + k, bf) * ldf(W2, k * 1024 + h * 256 + c, bf);
      v = 0.25f * a; }
    else if (r < 1400){ int q = r - 1312; int h = q / 22, te = q % 22; v = 0.25f * ldf(etemb2, te * 1024 + h * 256 + c, bf); }
    else if (r == 1400){ v = ldf(b2, c, bf); }
    M2T[c * K2V + r] = f2b(v);
  }
}

// ---------------- per-node attention scalars ----------------
__global__ void k_sd1(const void* x, const int* ntype, const float* fw, float* s1, float* d1,
                      const int4* flg){
  int4 f = *flg;
  int id = blockIdx.x * 256 + threadIdx.x;
  if (id >= NN * 4) return;
  int n = id >> 2, h = id & 3;
  float a = 0.f, d = 0.f;
  for (int k = 0; k < 64; k++){
    float xv = ldf(x, (size_t)n * 64 + k, f.x);
    a += xv * fw[FW_W1A + k * 4 + h]; d += xv * fw[FW_W1D + k * 4 + h];
  }
  int nt = geti(ntype, n, f.z);
  s1[id] = a + fw[FW_NTS1 + nt * 4 + h];
  d1[id] = d + fw[FW_NTD1 + nt * 4 + h];
}

__global__ void k_sd2(const u16* hbuf, const int* ntype, const float* fw, float* s2, float* d2,
                      const int4* flg){
  int4 f = *flg;
  int id = blockIdx.x * 256 + threadIdx.x;
  if (id >= NN * 4) return;
  int n = id >> 2, h = id & 3;
  float a = 0.f, d = 0.f;
  for (int k = 0; k < 256; k++){
    float xv = b2f(hbuf[n * 256 + k]);
    a += xv * fw[FW_W2A + k * 4 + h]; d += xv * fw[FW_W2D + k * 4 + h];
  }
  int nt = geti(ntype, n, f.z);
  s2[id] = a + fw[FW_NTS2 + nt * 4 + h];
  d2[id] = d + fw[FW_NTD2 + nt * 4 + h];
}

// ---------------- edge attention-logit contributions (both layers) ----------------
__global__ void k_el(const void* ea, const int* etype, const float* fw, float* el, const int4* flg){
  __shared__ float sw[512];
  __shared__ float sea[32 * 65];
  int4 f = *flg;
  int t = threadIdx.x;
  for (int i = t; i < 512; i += 256) sw[i] = fw[FW_WA12 + i];
  int e0 = blockIdx.x * 32;
  {
    int eloc = t >> 3, kc = (t & 7) * 8;
    float* dp = &sea[eloc * 65 + kc];
    if (f.x){
      const u16* p = (const u16*)ea + (size_t)(e0 + eloc) * 64 + kc;
      ushort4 a = *(const ushort4*)p;
      ushort4 b = *(const ushort4*)(p + 4);
      dp[0] = b2f(a.x); dp[1] = b2f(a.y); dp[2] = b2f(a.z); dp[3] = b2f(a.w);
      dp[4] = b2f(b.x); dp[5] = b2f(b.y); dp[6] = b2f(b.z); dp[7] = b2f(b.w);
    } else {
      const float* p = (const float*)ea + (size_t)(e0 + eloc) * 64 + kc;
      float4 a = *(const float4*)p;
      float4 b = *(const float4*)(p + 4);
      dp[0] = a.x; dp[1] = a.y; dp[2] = a.z; dp[3] = a.w;
      dp[4] = b.x; dp[5] = b.y; dp[6] = b.z; dp[7] = b.w;
    }
  }
  __syncthreads();
  int eloc = t >> 3, d = t & 7;
  int e = e0 + eloc;
  float a = 0.f;
  for (int k = 0; k < 64; k++) a += sea[eloc * 65 + k] * sw[k * 8 + d];
  int et = geti(etype, e, f.w);
  a += (d < 4) ? fw[FW_ETA1 + et * 4 + d] : fw[FW_ETA2 + et * 4 + (d - 4)];
  el[(size_t)e * 8 + d] = a;
}

// ---------------- layer-1 aggregation: one-pass softmax, one wave/node, 4 nodes/block ----------------
__global__ __launch_bounds__(256) void k_agg1(const int* off, const int4* meta,
    const float* el, const float* s1, const float* d1,
    const void* x, const void* ea, u16* V1, const int4* flg){
  int bf = flg->x;
  int n = blockIdx.x * 4 + (threadIdx.x >> 6);
  int lane = threadIdx.x & 63;
  int beg = off[n], end = off[n + 1];
  float4 dv = *(const float4*)&d1[n * 4];
  float dvh[4] = {dv.x, dv.y, dv.z, dv.w};

  // per-lane one-hot targets
  int ht1 = lane >> 3;             // 0..7 (valid <4)
  int c1  = lane & 7;
  int ht2a = lane / 22;            // 0..2
  int c2a  = lane - 22 * ht2a;
  bool v2b = (lane >= 2 && lane < 24);  // h=3 slots 66..87 -> lane+64
  int c2b  = lane - 2;

  float den[4] = {0.f, 0.f, 0.f, 0.f};
  float g1[4] = {0.f, 0.f, 0.f, 0.f};
  float g2[4] = {0.f, 0.f, 0.f, 0.f};
  float t1 = 0.f, t2a = 0.f, t2b = 0.f;
#pragma unroll 2
  for (int i = beg; i < end; i++){
    int4 md = meta[i];
    int eid = md.x, src = md.y, et = md.z, nt = md.w;
    float4 elv = *(const float4*)&el[(size_t)eid * 8];
    float4 sv  = *(const float4*)&s1[src * 4];
    float lg[4] = {sv.x + dvh[0] + elv.x, sv.y + dvh[1] + elv.y,
                   sv.z + dvh[2] + elv.z, sv.w + dvh[3] + elv.w};
    float pa[4];
#pragma unroll
    for (int h = 0; h < 4; h++){
      float l = lg[h]; l = fmaxf(l, 0.2f * l);
      float p = __expf(l);          // one-pass: logits bounded (leaky floor ~ -1, max ~ +6)
      den[h] += p; pa[h] = p;
    }
    float xv = ldf(x, (size_t)src * 64 + lane, bf);
    float ev = ldf(ea, (size_t)eid * 64 + lane, bf);
#pragma unroll
    for (int h = 0; h < 4; h++){ g1[h] += pa[h] * xv; g2[h] += pa[h] * ev; }
    // one-hot type sums via select chains
    float pt1 = (ht1 & 2) ? ((ht1 & 1) ? pa[3] : pa[2]) : ((ht1 & 1) ? pa[1] : pa[0]);
    t1  += ((ht1 < 4) && (nt == c1)) ? pt1 : 0.f;
    float p2a = (ht2a == 2) ? pa[2] : ((ht2a == 1) ? pa[1] : pa[0]);
    t2a += (et == c2a) ? p2a : 0.f;
    t2b += (v2b && (et == c2b)) ? pa[3] : 0.f;
  }
  float inv[4];
#pragma unroll
  for (int h = 0; h < 4; h++)
    inv[h] = (den[h] > 0.f) ? 1.f / (den[h] + 1e-16f) : 0.f;

  u16* vrow = &V1[(size_t)n * K1];
#pragma unroll
  for (int h = 0; h < 4; h++){
    vrow[h * 64 + lane]       = f2b(inv[h] * g1[h]);
    vrow[256 + h * 64 + lane] = f2b(inv[h] * g2[h]);
  }
  if (lane < 32) vrow[512 + lane] = f2b(inv[lane >> 3] * t1);
  vrow[544 + lane] = f2b(inv[ht2a] * t2a);
  if (lane < 24) vrow[608 + lane] = f2b(inv[3] * t2b * ((lane >= 2) ? 1.f : 0.f) + ((lane < 2) ? inv[2] * t2b : 0.f));
  vrow[632 + lane] = f2b(ldf(x, (size_t)n * 64 + lane, bf));
  if (lane == 0) vrow[696] = f2b(1.f);
  if (lane >= 1 && lane < 8) vrow[696 + lane] = 0;
}

// ---------------- layer-2 aggregation (node chunk): one-pass, one wave/node, 4/block ----------------
__global__ __launch_bounds__(256) void k_agg2(const int* off, const int4* meta,
    const float* el, const float* s2, const float* d2,
    const u16* hbuf, const void* ea, u16* V2, int nbase, const int4* flg){
  int bf = flg->x;
  int nl = blockIdx.x * 4 + (threadIdx.x >> 6);
  int n = nbase + nl;
  int lane = threadIdx.x & 63;
  int beg = off[n], end = off[n + 1];
  float4 dv = *(const float4*)&d2[n * 4];
  float dvh[4] = {dv.x, dv.y, dv.z, dv.w};

  int ht1 = lane >> 3;
  int c1  = lane & 7;
  int ht2a = lane / 22;
  int c2a  = lane - 22 * ht2a;
  bool v2b = (lane >= 2 && lane < 24);
  int c2b  = lane - 2;

  float den[4] = {0.f, 0.f, 0.f, 0.f};
  float g3[4][4] = {};
  float g4[4] = {0.f, 0.f, 0.f, 0.f};
  float t3 = 0.f, t4a = 0.f, t4b = 0.f;
#pragma unroll 2
  for (int i = beg; i < end; i++){
    int4 md = meta[i];
    int eid = md.x, src = md.y, et = md.z, nt = md.w;
    float4 elv = *(const float4*)&el[(size_t)eid * 8 + 4];
    float4 sv  = *(const float4*)&s2[src * 4];
    float lg[4] = {sv.x + dvh[0] + elv.x, sv.y + dvh[1] + elv.y,
                   sv.z + dvh[2] + elv.z, sv.w + dvh[3] + elv.w};
    float pa[4];
#pragma unroll
    for (int h = 0; h < 4; h++){
      float l = lg[h]; l = fmaxf(l, 0.2f * l);
      float p = __expf(l);
      den[h] += p; pa[h] = p;
    }
    ushort4 hv = *(const ushort4*)&hbuf[(size_t)src * 256 + lane * 4];
    float h0 = b2f(hv.x), h1 = b2f(hv.y), h2 = b2f(hv.z), h3 = b2f(hv.w);
    float ev = ldf(ea, (size_t)eid * 64 + lane, bf);
#pragma unroll
    for (int h = 0; h < 4; h++){
      float p = pa[h];
      g3[h][0] += p * h0; g3[h][1] += p * h1; g3[h][2] += p * h2; g3[h][3] += p * h3;
      g4[h] += p * ev;
    }
    float pt1 = (ht1 & 2) ? ((ht1 & 1) ? pa[3] : pa[2]) : ((ht1 & 1) ? pa[1] : pa[0]);
    t3  += ((ht1 < 4) && (nt == c1)) ? pt1 : 0.f;
    float p2a = (ht2a == 2) ? pa[2] : ((ht2a == 1) ? pa[1] : pa[0]);
    t4a += (et == c2a) ? p2a : 0.f;
    t4b += (v2b && (et == c2b)) ? pa[3] : 0.f;
  }
  float inv[4];
#pragma unroll
  for (int h = 0; h < 4; h++)
    inv[h] = (den[h] > 0.f) ? 1.f / (den[h] + 1e-16f) : 0.f;

  u16* vrow = &V2[(size_t)nl * K2V];
#pragma unroll
  for (int h = 0; h < 4; h++){
#pragma unroll
    for (int j = 0; j < 4; j++)
      vrow[h * 256 + lane * 4 + j] = f2b(inv[h] * g3[h][j]);
    vrow[1024 + h * 64 + lane] = f2b(inv[h] * g4[h]);
  }
  if (lane < 32) vrow[1280 + lane] = f2b(inv[lane >> 3] * t3);
  vrow[1312 + lane] = f2b(inv[ht2a] * t4a);
  if (lane < 24) vrow[1376 + lane] = f2b(inv[3] * t4b * ((lane >= 2) ? 1.f : 0.f) + ((lane < 2) ? inv[2] * t4b : 0.f));
  if (lane == 0) vrow[1400] = f2b(1.f);
  if (lane >= 1 && lane < 8) vrow[1400 + lane] = 0;
}

// ---------------- MFMA GEMM: C[rowbase+r,256] = A[r,:KK] @ Bt^T, fused epilogue ----------------
// MODE 1: relu -> bf16 hbuf.  MODE 2: + residual(hres) -> f32 out
typedef __bf16 bf16x8 __attribute__((ext_vector_type(8)));
typedef float  f32x4  __attribute__((ext_vector_type(4)));

template<int KK, int MODE>
__global__ __launch_bounds__(256) void k_gemm(const u16* A, const u16* Bt,
                                              const u16* hres, void* outv,
                                              int rowbase, int mcount){
  __shared__ __align__(16) u16 As[64 * 40];
  __shared__ __align__(16) u16 Bs[64 * 40];
  int t = threadIdx.x;
  int w = t >> 6, lane = t & 63;
  int m0 = blockIdx.x * 64, n0 = blockIdx.y * 64;
  int wm = w & 1, wn = w >> 1;
  f32x4 acc[2][2] = {};
  int ar = t >> 2, akc = (t & 3) * 8;
  for (int k0 = 0; k0 < KK; k0 += 32){
    {
      int row = m0 + ar;
      ushort4 v0 = {0, 0, 0, 0}, v1 = {0, 0, 0, 0};
      if (row < mcount){
        const u16* p = &A[(size_t)row * KK + k0 + akc];
        v0 = *(const ushort4*)p; v1 = *(const ushort4*)(p + 4);
      }
      *(ushort4*)&As[ar * 40 + akc] = v0;
      *(ushort4*)&As[ar * 40 + akc + 4] = v1;
      const u16* q = &Bt[(size_t)(n0 + ar) * KK + k0 + akc];
      ushort4 b0 = *(const ushort4*)q;
      ushort4 b1 = *(const ushort4*)(q + 4);
      *(ushort4*)&Bs[ar * 40 + akc] = b0;
      *(ushort4*)&Bs[ar * 40 + akc + 4] = b1;
    }
    __syncthreads();
    int kq = (lane >> 4) * 8;
    int ml = lane & 15;
    bf16x8 a0 = *(const bf16x8*)&As[(wm * 32 + ml) * 40 + kq];
    bf16x8 a1 = *(const bf16x8*)&As[(wm * 32 + 16 + ml) * 40 + kq];
    bf16x8 b0 = *(const bf16x8*)&Bs[(wn * 32 + ml) * 40 + kq];
    bf16x8 b1 = *(const bf16x8*)&Bs[(wn * 32 + 16 + ml) * 40 + kq];
    acc[0][0] = __builtin_amdgcn_mfma_f32_16x16x32_bf16(a0, b0, acc[0][0], 0, 0, 0);
    acc[0][1] = __builtin_amdgcn_mfma_f32_16x16x32_bf16(a0, b1, acc[0][1], 0, 0, 0);
    acc[1][0] = __builtin_amdgcn_mfma_f32_16x16x32_bf16(a1, b0, acc[1][0], 0, 0, 0);
    acc[1][1] = __builtin_amdgcn_mfma_f32_16x16x32_bf16(a1, b1, acc[1][1], 0, 0, 0);
    __syncthreads();
  }
  int quad = lane >> 4, col4 = lane & 15;
#pragma unroll
  for (int i = 0; i < 2; i++)
#pragma unroll
    for (int j = 0; j < 2; j++){
      int colG = n0 + wn * 32 + j * 16 + col4;
#pragma unroll
      for (int r = 0; r < 4; r++){
        int rowL = m0 + wm * 32 + i * 16 + quad * 4 + r;
        if (rowL < mcount){
          int rowG = rowbase + rowL;
          float v = acc[i][j][r];
          if (MODE == 1){
            v = fmaxf(v, 0.f);
            ((u16*)outv)[(size_t)rowG * 256 + colG] = f2b(v);
          } else {
            v += b2f(hres[(size_t)rowG * 256 + colG]);
            ((float*)outv)[(size_t)rowG * 256 + colG] = v;   // f32 output per reference dtype
          }
        }
      }
    }
}

// ---------------- launcher ----------------
extern "C" void kernel_launch(void* const* d_in, const int* in_sizes, int n_in,
                              void* d_out, int out_size, void* d_ws, size_t ws_size,
                              hipStream_t stream){
  const void* x      = d_in[0];
  const int*  ei     = (const int*)d_in[1];
  const int*  ntype  = (const int*)d_in[2];
  const void* ea     = d_in[3];
  const int*  etype  = (const int*)d_in[4];
  const void* l1_W     = d_in[5];
  const void* l1_b     = d_in[6];
  const void* l1_Wedge = d_in[7];
  const void* l1_ntemb = d_in[8];
  const void* l1_etemb = d_in[9];
  const void* l1_asrc  = d_in[10];
  const void* l1_adst  = d_in[11];
  const void* l1_aedge = d_in[12];
  const void* l1_res   = d_in[13];
  const void* l2_W     = d_in[14];
  const void* l2_b     = d_in[15];
  const void* l2_Wedge = d_in[16];
  const void* l2_ntemb = d_in[17];
  const void* l2_etemb = d_in[18];
  const void* l2_asrc  = d_in[19];
  const void* l2_adst  = d_in[20];
  const void* l2_aedge = d_in[21];

  char* ws = (char*)d_ws;
  int4*  flg    = (int4*)(ws + WS_FLG);
  int*   deg    = (int*)(ws + WS_DEG);
  int*   off    = (int*)(ws + WS_OFF);
  int*   cur    = (int*)(ws + WS_CUR);
  int4*  meta   = (int4*)(ws + WS_META);
  float* el     = (float*)(ws + WS_EL);
  float* s1     = (float*)(ws + WS_S1);
  float* d1     = (float*)(ws + WS_D1);
  float* s2     = (float*)(ws + WS_S2);
  float* d2     = (float*)(ws + WS_D2);
  float* fw     = (float*)(ws + WS_FW);
  u16*   M1T    = (u16*)(ws + WS_M1T);
  u16*   M2T    = (u16*)(ws + WS_M2T);
  u16*   hbuf   = (u16*)(ws + WS_HBUF);
  u16*   V      = (u16*)(ws + WS_V);

  hipLaunchKernelGGL(k_probe,   dim3(1),    dim3(64),  0, stream,
                     (const u16*)x, ei, ntype, etype, flg);
  hipLaunchKernelGGL(k_zero,    dim3(40),   dim3(256), 0, stream, deg);
  hipLaunchKernelGGL(k_hist,    dim3(1250), dim3(256), 0, stream, ei, deg, flg);
  hipLaunchKernelGGL(k_scan,    dim3(1),    dim3(256), 0, stream, deg, off, cur);
  hipLaunchKernelGGL(k_scatter, dim3(1250), dim3(256), 0, stream, ei, ntype, etype, cur, meta, flg);
  hipLaunchKernelGGL(k_fold_a,  dim3(8),    dim3(256), 0, stream,
                     l1_W, l1_Wedge, l1_asrc, l1_adst, l1_aedge, l1_etemb,
                     l2_W, l2_Wedge, l2_asrc, l2_adst, l2_aedge, l2_etemb, fw, flg);
  hipLaunchKernelGGL(k_fold_b,  dim3(1),    dim3(64),  0, stream, l1_ntemb, l2_ntemb, fw, flg);
  hipLaunchKernelGGL(k_m1t,     dim3(256),  dim3(256), 0, stream,
                     l1_W, l1_Wedge, l1_ntemb, l1_etemb, l1_res, l1_b, M1T, flg);
  hipLaunchKernelGGL(k_m2t,     dim3(256),  dim3(256), 0, stream,
                     l2_W, l2_Wedge, l2_ntemb, l2_etemb, l2_b, M2T, flg);
  hipLaunchKernelGGL(k_sd1,     dim3(157),  dim3(256), 0, stream, x, ntype, fw, s1, d1, flg);
  hipLaunchKernelGGL(k_el,      dim3(10000),dim3(256), 0, stream, ea, etype, fw, el, flg);
  hipLaunchKernelGGL(k_agg1,    dim3(2500), dim3(256), 0, stream, off, meta, el, s1, d1, x, ea, V, flg);
  hipLaunchKernelGGL((k_gemm<K1, 1>),  dim3(157, 4), dim3(256), 0, stream, V, M1T, hbuf, (void*)hbuf, 0, NN);
  hipLaunchKernelGGL(k_sd2,     dim3(157),  dim3(256), 0, stream, hbuf, ntype, fw, s2, d2, flg);
  for (int c = 0; c < 2; c++){
    int base = c * 5000;
    hipLaunchKernelGGL(k_agg2,  dim3(1250), dim3(256), 0, stream,
                       off, meta, el, s2, d2, hbuf, ea, V, base, flg);
    hipLaunchKernelGGL((k_gemm<K2V, 2>), dim3(79, 4), dim3(256), 0, stream,
                       V, M2T, hbuf, d_out, base, 5000);
  }
}